// Round 13
// baseline (242.621 us; speedup 1.0000x reference)
//
#include <hip/hip_runtime.h>
#include <math.h>

#define NIMG 64
#define SEQ  2602
#define EMB  128
#define HD   16
#define SPAD 2624    // SEQ padded to multiple of 64
#define KQ   96      // patch K padded 75 -> 96 (multiple of 32)
#define LSO  136     // LDS row stride (bf16) for K=128 (272 B, 16B-multiple)
#define TOK  4       // tokens per gemm_out_ln_pool block (651 blocks ~ 2.5/CU)

typedef float f32x4 __attribute__((ext_vector_type(4)));
typedef short short8 __attribute__((ext_vector_type(8)));

// round-half-up bf16 (2 VALU ops)
__device__ __forceinline__ unsigned short f2bf(float f) {
    union { float f; unsigned int u; } v; v.f = f;
    return (unsigned short)((v.u + 0x8000u) >> 16);
}

// ---------------------------------------------------------------------------
// A_pre[s][e]: s==0 -> cls + PE(0); 1<=s<SEQ -> lm_b + PE(s); else 0.
// ---------------------------------------------------------------------------
__global__ __launch_bounds__(128) void build_A(
    const float* __restrict__ lm_b, const float* __restrict__ cls,
    float* __restrict__ A) {
    const int s = blockIdx.x, e = threadIdx.x;
    const bool odd = e & 1;
    float v;
    if (s == 0) {
        v = cls[e] + (odd ? 1.0f : 0.0f);
    } else if (s < SEQ) {
        float pfac = powf(10000.0f, -(float)(e & ~1) / 128.0f);
        float ang = (float)s * pfac;
        v = lm_b[e] + (odd ? cosf(ang) : sinf(ang));
    } else {
        v = 0.0f;
    }
    A[(size_t)s * 128 + e] = v;
}

// ---------------------------------------------------------------------------
// W2[j][f] = sum_e w_in[j][e]*lm_w[e][f], f<75; zero-pad to KQ. bf16 out.
// ---------------------------------------------------------------------------
__global__ __launch_bounds__(128) void build_W2(
    const float* __restrict__ w_in, const float* __restrict__ lm_w,
    unsigned short* __restrict__ W2) {
    const int j = blockIdx.x, f = threadIdx.x;
    if (f >= KQ) return;
    float acc = 0.0f;
    if (f < 75) {
        for (int e = 0; e < 128; ++e)
            acc += w_in[j * 128 + e] * lm_w[e * 75 + f];
    }
    W2[j * KQ + f] = f2bf(acc);
}

__global__ __launch_bounds__(128) void build_Wout(
    const float* __restrict__ w_out, unsigned short* __restrict__ Wo) {
    const int j = blockIdx.x, e = threadIdx.x;
    Wo[j * 128 + e] = f2bf(w_out[j * 128 + e]);
}

__global__ __launch_bounds__(1024) void zero_pooled(float* __restrict__ p) {
    p[blockIdx.x * 1024 + threadIdx.x] = 0.0f;
}

// ---------------------------------------------------------------------------
// Patchify, coalesced both ends. Grid (52, 64): i<51 = patch rows;
// i==51 zeroes the cls-token row of Pb (token 0).
// ---------------------------------------------------------------------------
__global__ __launch_bounds__(256) void patchify(
    const float* __restrict__ images, unsigned short* __restrict__ Pb) {
    __shared__ unsigned short rows[15][256];
    const int i = blockIdx.x, l = blockIdx.y;
    const int tid = threadIdx.x;

    if (i == 51) {                    // cls row: Pb[0][l][*] = 0
        if (tid < 24)
            ((uint4*)(Pb + (size_t)l * KQ))[tid % 12] = make_uint4(0, 0, 0, 0);
        // note: 96 halves = 12 uint4; threads 0..11 write, rest idle
        return;
    }

    if (tid < 255) {
        #pragma unroll
        for (int seg = 0; seg < 15; ++seg) {
            int c = seg / 5, rr = seg % 5;
            float v = images[(((size_t)l * 3 + c) * 255 + (i * 5 + rr)) * 255 + tid];
            rows[seg][tid] = f2bf(v);
        }
    }
    __syncthreads();

    const int j = tid >> 2;          // token within this patch-row
    const int part = tid & 3;        // quarter of the 96-wide feature row
    if (j < 51) {
        const int f0 = part * 24;
        __align__(16) unsigned short buf[24];
        #pragma unroll
        for (int u = 0; u < 24; ++u) {
            int f = f0 + u;
            unsigned short v = 0;
            if (f < 75) {
                int c = f / 25, rem = f % 25, rr = rem / 5, cc = rem % 5;
                v = rows[c * 5 + rr][j * 5 + cc];
            }
            buf[u] = v;
        }
        const int s = i * 51 + j + 1;
        unsigned short* dst = Pb + ((size_t)s * 64 + l) * KQ + f0;
        #pragma unroll
        for (int t = 0; t < 3; ++t)
            *(short8*)(dst + t * 8) = *(const short8*)&buf[t * 8];
    }
}

// ---------------------------------------------------------------------------
// FUSED QKV-GEMM + attention. One block (4 waves) per token; wave w processes
// heads 2w and 2w+1 with wave-private LDS (13.25 KB/wave, 53 KB/block,
// 3 blocks/CU). The head loop is FULLY UNROLLED so head-1's phase-1 global
// loads + MFMAs interleave with head-0's softmax tail (different pipes).
// Correctness of LDS buffer reuse across heads relies on per-wave in-order
// DS execution at identical addresses. ZERO barriers.
// ---------------------------------------------------------------------------
__global__ __launch_bounds__(256, 3) void qkv_attn(
    const unsigned short* __restrict__ Pb, const unsigned short* __restrict__ W2,
    const float* __restrict__ SB, unsigned short* __restrict__ Obuf) {
    __shared__ __align__(16) unsigned short Qw_[4][64 * 24];
    __shared__ __align__(16) unsigned short Kw_[4][64 * 24];   // K, then O assembly
    __shared__ __align__(16) unsigned short Vw_[4][16 * 72];   // V transposed
    __shared__ __align__(16) unsigned short Pw_[4][64 * 40];   // half-P (64x32+pad)

    const int s = blockIdx.x;
    const int tid = threadIdx.x;
    const int w = tid >> 6, lane = tid & 63, quad = lane >> 4, col = lane & 15;
    unsigned short* Qw = Qw_[w];
    unsigned short* Kw = Kw_[w];
    unsigned short* Vw = Vw_[w];
    unsigned short* Pw = Pw_[w];

    const unsigned short* arow0 = Pb + (size_t)s * 64 * KQ;
    const float* sbrow = SB + (size_t)s * 384;
    short8 ones8;
    #pragma unroll
    for (int i = 0; i < 8; ++i) ones8[i] = (short)0x3F80;   // bf16 1.0

    #pragma unroll
    for (int hl = 0; hl < 2; ++hl) {
        const int h = 2 * w + hl;

        // ---- Phase 1: 48-channel sub-GEMM (Q/K/V 16-ch tiles for head h)
        f32x4 acc[3][4] = {};
        #pragma unroll
        for (int ks = 0; ks < 3; ++ks) {
            const int k0 = ks * 32 + quad * 8;
            short8 b[3];
            #pragma unroll
            for (int nt = 0; nt < 3; ++nt) {
                int ch = nt * 128 + h * 16 + col;
                b[nt] = *(const short8*)(W2 + (size_t)ch * KQ + k0);
            }
            #pragma unroll
            for (int mt = 0; mt < 4; ++mt) {
                short8 a = *(const short8*)(arow0 + (size_t)(mt * 16 + col) * KQ + k0);
                #pragma unroll
                for (int nt = 0; nt < 3; ++nt)
                    acc[nt][mt] = __builtin_amdgcn_mfma_f32_16x16x32_bf16(a, b[nt], acc[nt][mt], 0, 0, 0);
            }
        }

        // ---- Epilogue: bias + scatter to wave-private LDS
        #pragma unroll
        for (int nt = 0; nt < 3; ++nt) {
            float bv = sbrow[nt * 128 + h * 16 + col];
            #pragma unroll
            for (int mt = 0; mt < 4; ++mt) {
                #pragma unroll
                for (int r = 0; r < 4; ++r) {
                    int m = mt * 16 + quad * 4 + r;
                    float v = acc[nt][mt][r] + bv;
                    if (nt == 0) {
                        int pos = (col >> 3) ^ (quad & 1);
                        Qw[m * 24 + pos * 8 + (col & 7)] = f2bf(v * 0.125f);
                    } else if (nt == 1) {
                        int pos = (col >> 3) ^ (quad & 1);
                        Kw[m * 24 + pos * 8 + (col & 7)] = f2bf(v);
                    } else {
                        Vw[col * 72 + m] = f2bf(v);
                    }
                }
            }
        }

        // ---- K as B-frags (dup-K: quads 2,3 re-read k0..15; x2 folded in Q)
        short8 bfr[4];
        #pragma unroll
        for (int nt = 0; nt < 4; ++nt) {
            int m_ = nt * 16 + col;
            int pos = (quad & 1) ^ ((col >> 2) & 1);
            bfr[nt] = *(const short8*)&Kw[m_ * 24 + pos * 8];
        }

        // ---- QK^T
        f32x4 sc[4][4] = {};
        #pragma unroll
        for (int mt = 0; mt < 4; ++mt) {
            int m_ = mt * 16 + col;
            int pos = (quad & 1) ^ ((col >> 2) & 1);
            short8 afr = *(const short8*)&Qw[m_ * 24 + pos * 8];
            #pragma unroll
            for (int nt = 0; nt < 4; ++nt)
                sc[mt][nt] = __builtin_amdgcn_mfma_f32_16x16x32_bf16(afr, bfr[nt], sc[mt][nt], 0, 0, 0);
        }

        // ---- V B-frags
        short8 vfr[2];
        #pragma unroll
        for (int ks = 0; ks < 2; ++ks)
            vfr[ks] = *(const short8*)&Vw[col * 72 + ks * 32 + quad * 8];

        // ---- softmax-PV in two n-halves through the half-P buffer
        f32x4 o[4] = {}, sm[4] = {};
        #pragma unroll
        for (int half = 0; half < 2; ++half) {
            #pragma unroll
            for (int ntl = 0; ntl < 2; ++ntl) {
                int nt = half * 2 + ntl;
                #pragma unroll
                for (int mt = 0; mt < 4; ++mt) {
                    #pragma unroll
                    for (int r = 0; r < 4; ++r) {
                        int m = mt * 16 + quad * 4 + r;
                        int pos = (ntl * 2 + (col >> 3)) ^ quad;
                        Pw[m * 40 + pos * 8 + (col & 7)] = f2bf(__expf(sc[mt][nt][r]));
                    }
                }
            }
            #pragma unroll
            for (int mt = 0; mt < 4; ++mt) {
                int m_ = mt * 16 + col;
                int pos = quad ^ ((col >> 2) & 3);
                short8 pa = *(const short8*)&Pw[m_ * 40 + pos * 8];
                o[mt]  = __builtin_amdgcn_mfma_f32_16x16x32_bf16(pa, vfr[half], o[mt], 0, 0, 0);
                sm[mt] = __builtin_amdgcn_mfma_f32_16x16x32_bf16(pa, ones8, sm[mt], 0, 0, 0);
            }
        }

        // ---- normalize, assemble O in Kw (K consumed), coalesced store
        #pragma unroll
        for (int mt = 0; mt < 4; ++mt) {
            #pragma unroll
            for (int r = 0; r < 4; ++r) {
                float iv = __builtin_amdgcn_rcpf(sm[mt][r]);
                int l = mt * 16 + quad * 4 + r;
                int cc = (l * 2 + (col >> 3)) ^ ((l >> 2) & 3);
                Kw[cc * 8 + (col & 7)] = f2bf(o[mt][r] * iv);
            }
        }
        unsigned short* od = Obuf + ((size_t)s * 8 + h) * 1024;
        #pragma unroll
        for (int jj = 0; jj < 2; ++jj) {
            int cc = lane * 2 + jj;
            int cs = cc ^ ((lane >> 2) & 3);
            *(short8*)(od + cc * 8) = *(const short8*)&Kw[cs * 8];
        }
    }
}

// ---------------------------------------------------------------------------
// Fused out-proj + LayerNorm + mean-pool, TOK tokens per block.
// ---------------------------------------------------------------------------
__global__ __launch_bounds__(256) void gemm_out_ln_pool(
    const unsigned short* __restrict__ O, const unsigned short* __restrict__ Wo,
    const float* __restrict__ b_out, const float* __restrict__ ln_g,
    const float* __restrict__ ln_b, float* __restrict__ pooled) {
    __shared__ __align__(16) unsigned short As[2][64 * LSO];
    __shared__ __align__(16) unsigned short Bs[128 * LSO];
    const int tid = threadIdx.x;
    const int s0 = blockIdx.x * TOK;
    const int wv = tid >> 6, lane = tid & 63, quad = lane >> 4, col = lane & 15;

    #pragma unroll
    for (int t = 0; t < 8; ++t) {                 // Wo rows: 128 x 16 chunks
        int q = tid + t * 256;
        int row = q >> 4, c = q & 15;
        *(float4*)&Bs[row * LSO + c * 8] =
            *(const float4*)(Wo + (size_t)row * 128 + c * 8);
    }
    #pragma unroll
    for (int t = 0; t < 4; ++t) {                 // token s0 -> As[0]
        int q = tid + t * 256;
        int h = q >> 7, rem = q & 127, l = rem >> 1, jj = rem & 1;
        *(short8*)&As[0][l * LSO + h * 16 + jj * 8] =
            *(const short8*)(O + (size_t)s0 * 8192 + (size_t)q * 8);
    }
    __syncthreads();

    float gch[8], bch[8], boch[8];
    #pragma unroll
    for (int nt = 0; nt < 8; ++nt) {
        int ch = nt * 16 + col;
        gch[nt] = ln_g[ch]; bch[nt] = ln_b[ch]; boch[nt] = b_out[ch];
    }
    const int mrow = wv * 16 + col;
    const int l0 = wv * 16 + quad * 4;
    const int nT = (SEQ - s0 < TOK) ? (SEQ - s0) : TOK;
    float accum[8][4] = {};

    for (int tt = 0; tt < nT; ++tt) {
        if (tt + 1 < nT) {                        // prefetch next token
            const size_t sn = s0 + tt + 1;
            #pragma unroll
            for (int t = 0; t < 4; ++t) {
                int q = tid + t * 256;
                int h = q >> 7, rem = q & 127, l = rem >> 1, jj = rem & 1;
                *(short8*)&As[(tt + 1) & 1][l * LSO + h * 16 + jj * 8] =
                    *(const short8*)(O + sn * 8192 + (size_t)q * 8);
            }
        }
        const unsigned short* Ac = As[tt & 1];
        f32x4 acc[8] = {};
        #pragma unroll
        for (int ks = 0; ks < 4; ++ks) {
            const int k0 = ks * 32 + quad * 8;
            short8 a = *(const short8*)&Ac[mrow * LSO + k0];
            #pragma unroll
            for (int nt = 0; nt < 8; ++nt) {
                short8 b = *(const short8*)&Bs[(nt * 16 + col) * LSO + k0];
                acc[nt] = __builtin_amdgcn_mfma_f32_16x16x32_bf16(a, b, acc[nt], 0, 0, 0);
            }
        }
        #pragma unroll
        for (int r = 0; r < 4; ++r) {
            float yv[8];
            float s1 = 0.0f, s2 = 0.0f;
            #pragma unroll
            for (int nt = 0; nt < 8; ++nt) {
                yv[nt] = acc[nt][r] + boch[nt];
                s1 += yv[nt]; s2 += yv[nt] * yv[nt];
            }
            #pragma unroll
            for (int off = 1; off < 16; off <<= 1) {
                s1 += __shfl_xor(s1, off);
                s2 += __shfl_xor(s2, off);
            }
            float mu = s1 * (1.0f / 128.0f);
            float var = s2 * (1.0f / 128.0f) - mu * mu;
            float rinv = rsqrtf(var + 1e-5f);
            #pragma unroll
            for (int nt = 0; nt < 8; ++nt)
                accum[nt][r] += (yv[nt] - mu) * rinv * gch[nt] + bch[nt];
        }
        __syncthreads();
    }

    #pragma unroll
    for (int nt = 0; nt < 8; ++nt)
        #pragma unroll
        for (int r = 0; r < 4; ++r)
            atomicAdd(&pooled[(l0 + r) * 128 + nt * 16 + col], accum[nt][r]);
}

// ---------------------------------------------------------------------------
// fp32 GEMM (precompute only, SB = A_pre @ w_in^T + b_in).
// ---------------------------------------------------------------------------
__global__ __launch_bounds__(256) void gemm64(
    const float* __restrict__ A, int lda, const float* __restrict__ B,
    const float* __restrict__ bias, float* __restrict__ C, int ldc) {
    __shared__ float As[64 * 68];
    __shared__ float Bs[64 * 68];
    const int bm = blockIdx.y * 64;
    const int bn = blockIdx.x * 64;
    const int tid = threadIdx.x;
    const int tx = tid & 15, ty = tid >> 4;

    float acc[4][4] = {};

    for (int kk = 0; kk < 128; kk += 64) {
        __syncthreads();
        #pragma unroll
        for (int t = 0; t < 4; ++t) {
            int q = tid + t * 256;
            int row = q & 63, c4 = (q >> 6) << 2;
            float4 va = *(const float4*)(A + (size_t)(bm + row) * lda + kk + c4);
            As[(c4 + 0) * 68 + row] = va.x;
            As[(c4 + 1) * 68 + row] = va.y;
            As[(c4 + 2) * 68 + row] = va.z;
            As[(c4 + 3) * 68 + row] = va.w;
            float4 vb = *(const float4*)(B + (size_t)(bn + row) * 128 + kk + c4);
            Bs[(c4 + 0) * 68 + row] = vb.x;
            Bs[(c4 + 1) * 68 + row] = vb.y;
            Bs[(c4 + 2) * 68 + row] = vb.z;
            Bs[(c4 + 3) * 68 + row] = vb.w;
        }
        __syncthreads();
        #pragma unroll 4
        for (int k = 0; k < 64; ++k) {
            float4 av = *(const float4*)&As[k * 68 + (ty << 2)];
            float4 bv = *(const float4*)&Bs[k * 68 + (tx << 2)];
            acc[0][0] += av.x*bv.x; acc[0][1] += av.x*bv.y; acc[0][2] += av.x*bv.z; acc[0][3] += av.x*bv.w;
            acc[1][0] += av.y*bv.x; acc[1][1] += av.y*bv.y; acc[1][2] += av.y*bv.z; acc[1][3] += av.y*bv.w;
            acc[2][0] += av.z*bv.x; acc[2][1] += av.z*bv.y; acc[2][2] += av.z*bv.z; acc[2][3] += av.z*bv.w;
            acc[3][0] += av.w*bv.x; acc[3][1] += av.w*bv.y; acc[3][2] += av.w*bv.z; acc[3][3] += av.w*bv.w;
        }
    }

    float4 bv = *(const float4*)(bias + bn + (tx << 2));
    #pragma unroll
    for (int i = 0; i < 4; ++i) {
        float4 r;
        r.x = acc[i][0] + bv.x; r.y = acc[i][1] + bv.y;
        r.z = acc[i][2] + bv.z; r.w = acc[i][3] + bv.w;
        *(float4*)(C + (size_t)(bm + (ty << 2) + i) * ldc + bn + (tx << 2)) = r;
    }
}

__global__ __launch_bounds__(128) void classify(
    const float* __restrict__ pooled, const float* __restrict__ out_w,
    const float* __restrict__ out_b, float* __restrict__ out) {
    const int l = blockIdx.x, e = threadIdx.x;
    __shared__ float sp[EMB];
    sp[e] = pooled[l * EMB + e] * (1.0f / (float)SEQ);
    __syncthreads();
    if (e < 3) {
        float acc = out_b[e];
        #pragma unroll 16
        for (int k = 0; k < EMB; ++k) acc += sp[k] * out_w[e * EMB + k];
        out[l * 3 + e] = acc;
    }
}

extern "C" void kernel_launch(void* const* d_in, const int* in_sizes, int n_in,
                              void* d_out, int out_size, void* d_ws, size_t ws_size,
                              hipStream_t stream) {
    const float* images = (const float*)d_in[0];
    const float* lm_w   = (const float*)d_in[1];
    const float* lm_b   = (const float*)d_in[2];
    const float* cls    = (const float*)d_in[3];
    const float* w_in   = (const float*)d_in[4];
    const float* b_in   = (const float*)d_in[5];
    const float* w_out  = (const float*)d_in[6];
    const float* b_out  = (const float*)d_in[7];
    const float* ln_g   = (const float*)d_in[8];
    const float* ln_b   = (const float*)d_in[9];
    const float* out_w  = (const float*)d_in[10];
    const float* out_b  = (const float*)d_in[11];
    float* out = (float*)d_out;

    // Workspace (~80 MB of 256 MiB), all regions 16B-aligned:
    float* SB     = (float*)d_ws;                         // [SPAD][384] f32
    float* A_pre  = SB + (size_t)SPAD * 384;              // [SPAD][128] f32
    float* pooled = A_pre + (size_t)SPAD * 128;           // [64][128] f32
    unsigned short* W2   = (unsigned short*)(pooled + 64 * 128); // [384][KQ]
    unsigned short* Wout = W2 + (size_t)384 * KQ;         // [128][128]
    unsigned short* Pb   = Wout + 128 * 128;              // [SEQ][64][KQ]
    unsigned short* Obuf = Pb + (size_t)SEQ * 64 * KQ;    // [SEQ][8][64][16]

    build_A<<<dim3(SPAD), 128, 0, stream>>>(lm_b, cls, A_pre);
    gemm64<<<dim3(6, SPAD / 64), 256, 0, stream>>>(A_pre, 128, w_in, b_in, SB, 384);
    build_W2<<<dim3(384), 128, 0, stream>>>(w_in, lm_w, W2);
    build_Wout<<<dim3(128), 128, 0, stream>>>(w_out, Wout);
    zero_pooled<<<dim3(8), 1024, 0, stream>>>(pooled);

    patchify<<<dim3(52, 64), 256, 0, stream>>>(images, Pb);
    qkv_attn<<<dim3(SEQ), 256, 0, stream>>>(Pb, W2, SB, Obuf);
    gemm_out_ln_pool<<<dim3((SEQ + TOK - 1) / TOK), 256, 0, stream>>>(
        Obuf, Wout, b_out, ln_g, ln_b, pooled);
    classify<<<dim3(NIMG), 128, 0, stream>>>(pooled, out_w, out_b, out);
}